// Round 4
// baseline (228.184 us; speedup 1.0000x reference)
//
#include <hip/hip_runtime.h>

// WaveletTransform: Haar 2x2 on (8, 64, 512, 512) fp32 -> 4x (8, 64, 256, 256) fp32
// Memory-bound single pass. Per thread: 8 input cols x 2 rows (4x 16B nt loads)
// -> 4 output pixels per subband (4x 16B nt stores).
// Exact-cover launch: 524288 threads x 16 items, unroll 4 for MLP.

#define BB 8
#define CC 64
#define HH_ 512
#define WW_ 512
#define OUTH (HH_ / 2)
#define OUTW (WW_ / 2)

#define NTHREADS (2048 * 256)   // 524288
#define ITEMS 16                // total items 8,388,608 = NTHREADS * ITEMS

typedef float v4f __attribute__((ext_vector_type(4)));

__global__ __launch_bounds__(256) void haar2x2_kernel(
    const float* __restrict__ x, float* __restrict__ out)
{
    const size_t subband = (size_t)BB * CC * OUTH * OUTW;  // 33554432

    int idx = blockIdx.x * blockDim.x + threadIdx.x;

#pragma unroll 4
    for (int k = 0; k < ITEMS; ++k) {
        int t = idx + k * NTHREADS;
        int img = t >> 14;
        int rem = t & 16383;
        int ho  = rem >> 6;       // output row, 0..255
        int wo  = rem & 63;       // 8-column group index within the input row

        const float* rowbase = x + (size_t)img * HH_ * WW_ + (size_t)(2 * ho) * WW_;
        const v4f* r0p = reinterpret_cast<const v4f*>(rowbase) + wo * 2;
        const v4f* r1p = reinterpret_cast<const v4f*>(rowbase + WW_) + wo * 2;

        v4f r0a = __builtin_nontemporal_load(r0p);      // a0 b0 a1 b1
        v4f r0b = __builtin_nontemporal_load(r0p + 1);  // a2 b2 a3 b3
        v4f r1a = __builtin_nontemporal_load(r1p);      // c0 d0 c1 d1
        v4f r1b = __builtin_nontemporal_load(r1p + 1);  // c2 d2 c3 d3

        v4f ll, lh, hl, hh;

        // pixel 0
        {
            float s0 = r0a.x + r0a.y, d0 = r0a.x - r0a.y;
            float s1 = r1a.x + r1a.y, d1 = r1a.x - r1a.y;
            ll.x = (s0 + s1) * 0.5f; lh.x = (s0 - s1) * 0.5f;
            hl.x = (d0 + d1) * 0.5f; hh.x = (d0 - d1) * 0.5f;
        }
        // pixel 1
        {
            float s0 = r0a.z + r0a.w, d0 = r0a.z - r0a.w;
            float s1 = r1a.z + r1a.w, d1 = r1a.z - r1a.w;
            ll.y = (s0 + s1) * 0.5f; lh.y = (s0 - s1) * 0.5f;
            hl.y = (d0 + d1) * 0.5f; hh.y = (d0 - d1) * 0.5f;
        }
        // pixel 2
        {
            float s0 = r0b.x + r0b.y, d0 = r0b.x - r0b.y;
            float s1 = r1b.x + r1b.y, d1 = r1b.x - r1b.y;
            ll.z = (s0 + s1) * 0.5f; lh.z = (s0 - s1) * 0.5f;
            hl.z = (d0 + d1) * 0.5f; hh.z = (d0 - d1) * 0.5f;
        }
        // pixel 3
        {
            float s0 = r0b.z + r0b.w, d0 = r0b.z - r0b.w;
            float s1 = r1b.z + r1b.w, d1 = r1b.z - r1b.w;
            ll.w = (s0 + s1) * 0.5f; lh.w = (s0 - s1) * 0.5f;
            hl.w = (d0 + d1) * 0.5f; hh.w = (d0 - d1) * 0.5f;
        }

        size_t obase = (size_t)img * OUTH * OUTW + (size_t)ho * OUTW + (size_t)(wo * 4);
        __builtin_nontemporal_store(ll, reinterpret_cast<v4f*>(out + 0 * subband + obase));
        __builtin_nontemporal_store(lh, reinterpret_cast<v4f*>(out + 1 * subband + obase));
        __builtin_nontemporal_store(hl, reinterpret_cast<v4f*>(out + 2 * subband + obase));
        __builtin_nontemporal_store(hh, reinterpret_cast<v4f*>(out + 3 * subband + obase));
    }
}

extern "C" void kernel_launch(void* const* d_in, const int* in_sizes, int n_in,
                              void* d_out, int out_size, void* d_ws, size_t ws_size,
                              hipStream_t stream) {
    const float* x = (const float*)d_in[0];
    float* out = (float*)d_out;

    haar2x2_kernel<<<2048, 256, 0, stream>>>(x, out);
}

// Round 5
// 197.188 us; speedup vs baseline: 1.1572x; 1.1572x over previous
//
#include <hip/hip_runtime.h>

// WaveletTransform: Haar 2x2 on (8, 64, 512, 512) fp32 -> 4x (8, 64, 256, 256) fp32
// Memory-bound single pass. Per thread: 8 input cols x 2 rows (4x 16B cached loads)
// -> 4 output pixels per subband (4x 16B nontemporal stores).
// R5: R3 structure, nt removed from loads (half-line-per-instr reads must merge in L2).

#define BB 8
#define CC 64
#define HH_ 512
#define WW_ 512
#define OUTH (HH_ / 2)
#define OUTW (WW_ / 2)

typedef float v4f __attribute__((ext_vector_type(4)));

__global__ __launch_bounds__(256) void haar2x2_kernel(
    const float* __restrict__ x, float* __restrict__ out, int total)
{
    // per-image work: OUTH row-pairs * (WW_/8) octs = 256 * 64 = 16384 = 2^14
    const size_t subband = (size_t)BB * CC * OUTH * OUTW;  // 33554432

    int idx = blockIdx.x * blockDim.x + threadIdx.x;
    int stride = gridDim.x * blockDim.x;

    for (int t = idx; t < total; t += stride) {
        int img = t >> 14;
        int rem = t & 16383;
        int ho  = rem >> 6;       // output row, 0..255
        int wo  = rem & 63;       // 8-column group index within the input row

        const float* rowbase = x + (size_t)img * HH_ * WW_ + (size_t)(2 * ho) * WW_;
        const v4f* r0p = reinterpret_cast<const v4f*>(rowbase) + wo * 2;
        const v4f* r1p = reinterpret_cast<const v4f*>(rowbase + WW_) + wo * 2;

        v4f r0a = r0p[0];   // a0 b0 a1 b1
        v4f r0b = r0p[1];   // a2 b2 a3 b3
        v4f r1a = r1p[0];   // c0 d0 c1 d1
        v4f r1b = r1p[1];   // c2 d2 c3 d3

        v4f ll, lh, hl, hh;

        // pixel 0
        {
            float s0 = r0a.x + r0a.y, d0 = r0a.x - r0a.y;
            float s1 = r1a.x + r1a.y, d1 = r1a.x - r1a.y;
            ll.x = (s0 + s1) * 0.5f; lh.x = (s0 - s1) * 0.5f;
            hl.x = (d0 + d1) * 0.5f; hh.x = (d0 - d1) * 0.5f;
        }
        // pixel 1
        {
            float s0 = r0a.z + r0a.w, d0 = r0a.z - r0a.w;
            float s1 = r1a.z + r1a.w, d1 = r1a.z - r1a.w;
            ll.y = (s0 + s1) * 0.5f; lh.y = (s0 - s1) * 0.5f;
            hl.y = (d0 + d1) * 0.5f; hh.y = (d0 - d1) * 0.5f;
        }
        // pixel 2
        {
            float s0 = r0b.x + r0b.y, d0 = r0b.x - r0b.y;
            float s1 = r1b.x + r1b.y, d1 = r1b.x - r1b.y;
            ll.z = (s0 + s1) * 0.5f; lh.z = (s0 - s1) * 0.5f;
            hl.z = (d0 + d1) * 0.5f; hh.z = (d0 - d1) * 0.5f;
        }
        // pixel 3
        {
            float s0 = r0b.z + r0b.w, d0 = r0b.z - r0b.w;
            float s1 = r1b.z + r1b.w, d1 = r1b.z - r1b.w;
            ll.w = (s0 + s1) * 0.5f; lh.w = (s0 - s1) * 0.5f;
            hl.w = (d0 + d1) * 0.5f; hh.w = (d0 - d1) * 0.5f;
        }

        size_t obase = (size_t)img * OUTH * OUTW + (size_t)ho * OUTW + (size_t)(wo * 4);
        __builtin_nontemporal_store(ll, reinterpret_cast<v4f*>(out + 0 * subband + obase));
        __builtin_nontemporal_store(lh, reinterpret_cast<v4f*>(out + 1 * subband + obase));
        __builtin_nontemporal_store(hl, reinterpret_cast<v4f*>(out + 2 * subband + obase));
        __builtin_nontemporal_store(hh, reinterpret_cast<v4f*>(out + 3 * subband + obase));
    }
}

extern "C" void kernel_launch(void* const* d_in, const int* in_sizes, int n_in,
                              void* d_out, int out_size, void* d_ws, size_t ws_size,
                              hipStream_t stream) {
    const float* x = (const float*)d_in[0];
    float* out = (float*)d_out;

    const int total = BB * CC * OUTH * (WW_ / 8);  // 8,388,608 work items
    const int block = 256;
    const int grid = 2048;

    haar2x2_kernel<<<grid, block, 0, stream>>>(x, out, total);
}